// Round 8
// baseline (178.670 us; speedup 1.0000x reference)
//
#include <hip/hip_runtime.h>
#include <hip/hip_bf16.h>

// TurnGPT attention block: y = proj(softmax(causal(QK^T/8)) V), qkv = x@W_attn+b
// B=2, T=2048, C=1024, H=16, D=64. d_in/d_out are FP32; bf16 MFMA inside.
// Q pre-scaled by 0.125*log2(e) at the qkv epilogue: attn p = exp2(s) raw.
// qkv: 256x192 tile, BK=64 (grid 16x16 = 1 block/CU), 8 waves, acc[4][6] (r7).
// attn: swapped QK^T (mfma(K,Q)) -> P is lane-local (q=l15), PV consumes it
//   directly with a k-permutation absorbed into V's b64 reads. No P LDS
//   round-trip (was: exp2->cvt->8x ds_write_b16->ds_read_b128->MFMA chain).
// proj single-buf (r1), attn qt-paired (r1), Vt ushort4-packed epilogue (r2).
// Hand-scheduled vmcnt pipelines REGRESSED (r3) -> plain __syncthreads only.

typedef __bf16 bf16_t;
typedef __bf16 bf16x8 __attribute__((ext_vector_type(8)));
typedef __bf16 bf16x4 __attribute__((ext_vector_type(4)));
typedef float f32x4 __attribute__((ext_vector_type(4)));
typedef unsigned short ushort_t;

#define QSCALE 0.18033688011f   // 0.125 * log2(e)

__device__ __forceinline__ void glds16(const bf16_t* g, ushort_t* l) {
  __builtin_amdgcn_global_load_lds(
      (const __attribute__((address_space(1))) unsigned int*)g,
      (__attribute__((address_space(3))) unsigned int*)l, 16, 0, 0);
}

// ---------------- fused prep: cvt(x) + transpose_cvt(W_attn) + (W_proj) ------
__global__ __launch_bounds__(256) void prep_kernel(
    const float* __restrict__ x, const float* __restrict__ W_attn,
    const float* __restrict__ W_proj, ushort_t* __restrict__ Xb,
    ushort_t* __restrict__ WtA, ushort_t* __restrict__ WtP) {
  const int bid = blockIdx.x, tid = threadIdx.x;
  if (bid < 4096) {
    int i = bid * 256 + tid;
    float4 v = ((const float4*)x)[i];
    ushort4 o;
    o.x = __builtin_bit_cast(unsigned short, (bf16_t)v.x);
    o.y = __builtin_bit_cast(unsigned short, (bf16_t)v.y);
    o.z = __builtin_bit_cast(unsigned short, (bf16_t)v.z);
    o.w = __builtin_bit_cast(unsigned short, (bf16_t)v.w);
    ((ushort4*)Xb)[i] = o;
    return;
  }
  __shared__ ushort_t tile[32][33];
  const float* in;
  ushort_t* out;
  int C, bx, by;
  if (bid < 4096 + 3072) { int idx = bid - 4096; in = W_attn; out = WtA; C = 3072; bx = idx % 96; by = idx / 96; }
  else                   { int idx = bid - 7168; in = W_proj; out = WtP; C = 1024; bx = idx % 32; by = idx / 32; }
  const int tx = tid & 31, ty = tid >> 5;
  int cbase = bx * 32, rbase = by * 32;
#pragma unroll
  for (int i = ty; i < 32; i += 8)
    tile[i][tx] = __builtin_bit_cast(
        unsigned short, (bf16_t)in[(size_t)(rbase + i) * C + cbase + tx]);
  __syncthreads();
#pragma unroll
  for (int i = ty; i < 32; i += 8)
    out[(size_t)(cbase + i) * 1024 + rbase + tx] = tile[tx][i];
}

// ------- QKV GEMM: Xb[4096,1024] @ W_attn + b, 256x192 tiles, BK=64 ----------
__global__ __launch_bounds__(512) void qkv_gemm_kernel(
    const bf16_t* __restrict__ X, const bf16_t* __restrict__ WtA,
    const float* __restrict__ bias, bf16_t* __restrict__ Qd,
    bf16_t* __restrict__ Kd, bf16_t* __restrict__ Vtd) {
  __shared__ ushort_t As[2 * 2 * 256 * 32];   // 64 KB: buf stride 16384
  __shared__ ushort_t Bs[2 * 2 * 192 * 32];   // 48 KB: buf stride 12288
  const int tid  = threadIdx.x;
  const int lane = tid & 63, wave = tid >> 6;
  const int l15  = lane & 15, quad = lane >> 4;
  const int wrow = (wave >> 1) * 64;      // 4 M-waves: 0,64,128,192
  const int wcol = (wave & 1) * 96;       // 2 N-waves: 0,96
  const int mtile = blockIdx.x * 256, ntile = blockIdx.y * 192;
  const int K = 1024;
  const int lr4 = lane >> 2;                               // row in stripe
  const int csw = ((lane & 3) ^ ((lr4 >> 1) & 3)) * 8;     // swizzled src col
  const int rsw = (quad ^ ((l15 >> 1) & 3)) * 8;           // swizzled read
  const bf16_t* Xrow = X   + (size_t)(mtile + lr4) * K + csw;
  const bf16_t* Wrow = WtA + (size_t)(ntile + lr4) * K + csw;

#define STAGE_QKV(kb, Asl, Bsl)                                              \
  {                                                                          \
    _Pragma("unroll")                                                        \
    for (int kk = 0; kk < 7; kk++) {                                         \
      int s = wave + kk * 8;                                                 \
      if (s < 32) {                                                          \
        int hh = s >> 4, r16 = s & 15;                                       \
        glds16(Xrow + (size_t)(r16 * 16) * K + (kb) + hh * 32,               \
               (Asl) + hh * 8192 + r16 * 512);                               \
      } else {                                                               \
        int sb = s - 32;                                                     \
        int hh = (sb >= 12) ? 1 : 0, r12 = sb - hh * 12;                     \
        glds16(Wrow + (size_t)(r12 * 16) * K + (kb) + hh * 32,               \
               (Bsl) + hh * 6144 + r12 * 512);                               \
      }                                                                      \
    }                                                                        \
  }

  f32x4 acc[4][6] = {};
  STAGE_QKV(0, As, Bs);                    // prologue: kt=0 -> buf 0
  __syncthreads();
  for (int kt = 0; kt < 16; kt++) {
    const int cur = kt & 1, nxt = cur ^ 1;
    if (kt + 1 < 16)                       // issue prefetch FIRST
      STAGE_QKV((kt + 1) * 64, As + nxt * 16384, Bs + nxt * 12288);
#pragma unroll
    for (int hh = 0; hh < 2; hh++) {
      bf16x8 af[4], bfr[6];
#pragma unroll
      for (int i = 0; i < 4; i++)
        af[i] = *(const bf16x8*)&As[cur * 16384 + hh * 8192 + (wrow + i * 16 + l15) * 32 + rsw];
#pragma unroll
      for (int j = 0; j < 6; j++)
        bfr[j] = *(const bf16x8*)&Bs[cur * 12288 + hh * 6144 + (wcol + j * 16 + l15) * 32 + rsw];
#pragma unroll
      for (int i = 0; i < 4; i++)
#pragma unroll
        for (int j = 0; j < 6; j++)
          acc[i][j] = __builtin_amdgcn_mfma_f32_16x16x32_bf16(af[i], bfr[j], acc[i][j], 0, 0, 0);
    }
    __syncthreads();          // drains prefetch vmcnt AFTER compute + barrier
  }
#undef STAGE_QKV

  const int b = mtile >> 11;               // block-uniform (256 | 2048)
#pragma unroll
  for (int j = 0; j < 6; j++) {
    int n = ntile + wcol + j * 16 + l15;   // [0,3072)
    float bv = bias[n];
    int sec = n >> 10, cc = n & 1023, h = cc >> 6, d = cc & 63;
    size_t bh = (size_t)(b * 16 + h);
    if (sec == 2) {
#pragma unroll
      for (int i = 0; i < 4; i++) {
        int tbase = (mtile & 2047) + wrow + i * 16 + quad * 4;
        ushort4 o4;
        o4.x = __builtin_bit_cast(unsigned short, (bf16_t)(acc[i][j][0] + bv));
        o4.y = __builtin_bit_cast(unsigned short, (bf16_t)(acc[i][j][1] + bv));
        o4.z = __builtin_bit_cast(unsigned short, (bf16_t)(acc[i][j][2] + bv));
        o4.w = __builtin_bit_cast(unsigned short, (bf16_t)(acc[i][j][3] + bv));
        *(ushort4*)&Vtd[(bh * 64 + d) * 2048 + tbase] = o4;
      }
    } else {
      const float sv = (sec == 0) ? QSCALE : 1.0f;
      bf16_t* Od = (sec == 0) ? Qd : Kd;
#pragma unroll
      for (int i = 0; i < 4; i++) {
#pragma unroll
        for (int r = 0; r < 4; r++) {
          int t = (mtile & 2047) + wrow + i * 16 + quad * 4 + r;
          Od[(bh * 2048 + t) * 64 + d] = (bf16_t)((acc[i][j][r] + bv) * sv);
        }
      }
    }
  }
}

// ---------------- flash attention: swapped QK^T, P in-register --------------
// Swapped QK (mfma(K,Q)): score tile C[k][q]: lane col l15 = q, rows
// quad*4+r = k (within 16). So each lane holds 8 P-values of ONE q-row
// (k = bn*16 + quad*4 + r). PV's A-operand slot e expects k = quad*8+e;
// feed it P[pi(k)] with pi(quad*8+e) = quad*4+(e&3)+16*(e>>2) and read V's
// B-operand through the same pi (two b64 reads at k in {quad*4..+3} and
// {16+quad*4..+3}). Sum over k is permutation-invariant -> exact.
// Softmax denom: one scalar per lane (q=l15), reduced via shfl_xor(16,32).
// qt pairing (r1): blocks y<16 get qt=15-x, y>=16 get qt=x -> uniform 34
// tile-units per CU.
__global__ __launch_bounds__(512) void attn_kernel(
    const bf16_t* __restrict__ Q, const bf16_t* __restrict__ K,
    const bf16_t* __restrict__ Vt, bf16_t* __restrict__ Y) {
  __shared__ ushort_t Ks[2][4096];       // [buf][kc*2048 + t*32 + chunk]
  __shared__ ushort_t Vs[2][4096];       // [buf][tHalf*2048 + d*32 + chunk]
  const int bh = blockIdx.y;
  const int qt = (blockIdx.y < 16) ? (15 - (int)blockIdx.x) : (int)blockIdx.x;
  const int tid = threadIdx.x, wave = tid >> 6, lane = tid & 63;
  const int l15 = lane & 15, quad = lane >> 4;
  const bf16_t* Qh = Q + (size_t)bh * 2048 * 64;
  const bf16_t* Kh = K + (size_t)bh * 2048 * 64;
  const bf16_t* Vh = Vt + (size_t)bh * 64 * 2048;
  const int b = bh >> 4, h = bh & 15;
  const int qw = qt * 128 + wave * 16;   // wave's q-row base
  const int nkt = 2 * qt + 2;            // 64-wide k-tiles

  bf16x8 qa[2];
#pragma unroll
  for (int kc = 0; kc < 2; kc++)
    qa[kc] = *(const bf16x8*)(Qh + (size_t)(qw + l15) * 64 + kc * 32 + quad * 8);

  f32x4 o[4] = {};
  float lp = 0.f;                        // denom for q = qw + l15
  const int rsw = (quad ^ ((l15 >> 1) & 3)) * 8;   // swizzled read chunk
  const int sw4 = (l15 >> 1) & 3;
  // V b64 read offsets within a row (pi-permuted k slots):
  const int vlo_off = (((quad >> 1) ^ sw4) * 8) + (quad & 1) * 4;        // k=quad*4..+3
  const int vhi_off = ((((quad >> 1) + 2) ^ sw4) * 8) + (quad & 1) * 4;  // k=16+quad*4..+3

  // staging: waves 0-3 -> K, waves 4-7 -> V; 2 glds16/wave/tile, swizzled cols
  const int lr4 = lane >> 2;
  const int csw = ((lane & 3) ^ ((lr4 >> 1) & 3)) * 8;
  const bool isK = wave < 4;
  const int sw = isK ? wave : wave - 4;
  const int rbase = (sw & 1) * 32;
  const bf16_t* gp0;
  size_t rowstep;
  if (isK) { gp0 = Kh + (size_t)(rbase + lr4) * 64 + (sw >> 1) * 32 + csw;  rowstep = 64; }
  else     { gp0 = Vh + (size_t)(rbase + lr4) * 2048 + (sw >> 1) * 32 + csw; rowstep = 2048; }
  const size_t kstep = isK ? (size_t)64 * 64 : 64;
  ushort_t* dst0 = (isK ? Ks[0] : Vs[0]) + (sw >> 1) * 2048 + rbase * 32;
  ushort_t* dst1 = (isK ? Ks[1] : Vs[1]) + (sw >> 1) * 2048 + rbase * 32;

#pragma unroll
  for (int c = 0; c < 2; c++)                       // prologue: tile 0 -> buf 0
    glds16(gp0 + (size_t)(c * 16) * rowstep, dst0 + c * 512);

  f32x4 zz = {0.f, 0.f, 0.f, 0.f};
  for (int kt = 0; kt < nkt; kt++) {
    const int cur = kt & 1;
    __syncthreads();                                // cur buf visible
    if (kt + 1 < nkt) {
      ushort_t* nd = cur ? dst0 : dst1;
#pragma unroll
      for (int c = 0; c < 2; c++)
        glds16(gp0 + (size_t)(kt + 1) * kstep + (size_t)(c * 16) * rowstep, nd + c * 512);
    }
#pragma unroll
    for (int h32 = 0; h32 < 2; h32++) {
      const int kb32 = kt * 64 + h32 * 32;          // sub-tile k base
      if (kb32 > qw + 15) break;                    // wave-uniform skip
      bf16x8 kb[2][2];
#pragma unroll
      for (int bn = 0; bn < 2; bn++)
#pragma unroll
        for (int kc = 0; kc < 2; kc++)
          kb[bn][kc] = *(const bf16x8*)&Ks[cur][kc * 2048 + (h32 * 32 + bn * 16 + l15) * 32 + rsw];
      f32x4 s[2];
#pragma unroll
      for (int bn = 0; bn < 2; bn++) {              // SWAPPED: K as A, Q as B
        f32x4 t0 = __builtin_amdgcn_mfma_f32_16x16x32_bf16(kb[bn][0], qa[0], zz, 0, 0, 0);
        s[bn] = __builtin_amdgcn_mfma_f32_16x16x32_bf16(kb[bn][1], qa[1], t0, 0, 0, 0);
      }
      const bool dg = (kb32 + 31 > qw);
      const int qrow = qw + l15;                    // this lane's q-row
      bf16x8 pa;
#pragma unroll
      for (int r = 0; r < 4; r++) {
        float v0 = s[0][r];                         // k = kb32 + quad*4 + r
        float v1 = s[1][r];                         // k = kb32 + 16 + quad*4 + r
        if (dg) {
          int k0 = kb32 + quad * 4 + r;
          if (k0 > qrow) v0 = -1e5f;
          if (k0 + 16 > qrow) v1 = -1e5f;
        }
        float p0 = __builtin_amdgcn_exp2f(v0);      // Q pre-scaled: exp2-domain
        float p1 = __builtin_amdgcn_exp2f(v1);
        lp += p0 + p1;
        pa[r]     = (bf16_t)p0;                     // A slot e=r   -> k=quad*4+r
        pa[4 + r] = (bf16_t)p1;                     // A slot e=4+r -> k=16+quad*4+r
      }
#pragma unroll
      for (int ns = 0; ns < 4; ns++) {
        const int rowoff = h32 * 2048 + (ns * 16 + l15) * 32;
        bf16x4 vlo = *(const bf16x4*)&Vs[cur][rowoff + vlo_off];
        bf16x4 vhi = *(const bf16x4*)&Vs[cur][rowoff + vhi_off];
        bf16x8 vb = __builtin_shufflevector(vlo, vhi, 0, 1, 2, 3, 4, 5, 6, 7);
        o[ns] = __builtin_amdgcn_mfma_f32_16x16x32_bf16(pa, vb, o[ns], 0, 0, 0);
      }
    }
  }
  // epilogue: reduce lp across quads (q=l15), redistribute to C layout rows
  lp += __shfl_xor(lp, 16);
  lp += __shfl_xor(lp, 32);
  float inv_l = 1.0f / fmaxf(lp, 1e-30f);
#pragma unroll
  for (int r = 0; r < 4; r++) {
    float il = __shfl(inv_l, quad * 4 + r);         // l for q-row quad*4+r
    int t = qw + quad * 4 + r;
#pragma unroll
    for (int ns = 0; ns < 4; ns++) {
      int c = h * 64 + ns * 16 + l15;
      Y[((size_t)(b * 2048 + t)) * 1024 + c] = (bf16_t)(o[ns][r] * il);
    }
  }
}

// ---------------- proj GEMM: 128x64 tiles, single-buf 2-barrier (round-1) ----
__global__ __launch_bounds__(256) void proj_gemm_kernel(
    const bf16_t* __restrict__ Yb, const bf16_t* __restrict__ WtP,
    const float* __restrict__ bias, float* __restrict__ out) {
  __shared__ ushort_t As[128 * 32];
  __shared__ ushort_t Bs[64 * 32];
  const int tid = threadIdx.x;
  const int lane = tid & 63, wave = tid >> 6;
  const int l15 = lane & 15, quad = lane >> 4;
  const int wrow = (wave >> 1) * 64, wcol = (wave & 1) * 32;
  const int mtile = blockIdx.x * 128, ntile = blockIdx.y * 64;
  const int K = 1024;
  const int lr = lane >> 2;
  const int lc = (((lane & 3) ^ ((lr >> 1) & 3)) * 8);
  const bf16_t* Ap = Yb + (size_t)(mtile + wave * 32 + lr) * K + lc;
  const bf16_t* Bp = WtP + (size_t)(ntile + wave * 16 + lr) * K + lc;
  const int rsw = (quad ^ ((l15 >> 1) & 3)) * 8;
  ushort_t* Asw = As + wave * 32 * 32;
  ushort_t* Bsw = Bs + wave * 16 * 32;
  f32x4 acc[4][2] = {};
  for (int kb = 0; kb < K; kb += 32) {
    __syncthreads();
    glds16(Ap + kb, Asw);
    glds16(Ap + (size_t)16 * K + kb, Asw + 16 * 32);
    glds16(Bp + kb, Bsw);
    __syncthreads();
    bf16x8 af[4], bfr[2];
#pragma unroll
    for (int i = 0; i < 4; i++)
      af[i] = *(const bf16x8*)&As[(wrow + i * 16 + l15) * 32 + rsw];
#pragma unroll
    for (int j = 0; j < 2; j++)
      bfr[j] = *(const bf16x8*)&Bs[(wcol + j * 16 + l15) * 32 + rsw];
#pragma unroll
    for (int i = 0; i < 4; i++)
#pragma unroll
      for (int j = 0; j < 2; j++)
        acc[i][j] = __builtin_amdgcn_mfma_f32_16x16x32_bf16(af[i], bfr[j], acc[i][j], 0, 0, 0);
  }
#pragma unroll
  for (int j = 0; j < 2; j++) {
    int n = ntile + wcol + j * 16 + l15;
    float bv = bias[n];
#pragma unroll
    for (int i = 0; i < 4; i++) {
#pragma unroll
      for (int r = 0; r < 4; r++) {
        int m = mtile + wrow + i * 16 + quad * 4 + r;
        out[(size_t)m * 1024 + n] = acc[i][j][r] + bv;
      }
    }
  }
}

extern "C" void kernel_launch(void* const* d_in, const int* in_sizes, int n_in,
                              void* d_out, int out_size, void* d_ws, size_t ws_size,
                              hipStream_t stream) {
  const float* x      = (const float*)d_in[0];   // [2,2048,1024]
  const float* W_attn = (const float*)d_in[1];   // [1024,3072]
  const float* b_attn = (const float*)d_in[2];   // [3072]
  const float* W_proj = (const float*)d_in[3];   // [1024,1024]
  const float* b_proj = (const float*)d_in[4];   // [1024]
  float* out = (float*)d_out;                    // [2,2048,1024]

  bf16_t* ws  = (bf16_t*)d_ws;
  bf16_t* WtA = ws;                                // 3072*1024
  bf16_t* WtP = WtA + (size_t)3072 * 1024;         // 1024*1024
  bf16_t* Xb  = WtP + (size_t)1024 * 1024;         // 4096*1024
  bf16_t* Qb  = Xb + (size_t)4194304;
  bf16_t* Kb  = Qb + (size_t)4194304;
  bf16_t* Vtb = Kb + (size_t)4194304;
  bf16_t* Yb  = Vtb + (size_t)4194304;             // ~48 MB bf16 total

  prep_kernel<<<8192, 256, 0, stream>>>(x, W_attn, W_proj,
      (ushort_t*)Xb, (ushort_t*)WtA, (ushort_t*)WtP);
  qkv_gemm_kernel<<<dim3(16, 16), 512, 0, stream>>>(Xb, WtA, b_attn, Qb, Kb, Vtb);
  attn_kernel<<<dim3(16, 32), 512, 0, stream>>>(Qb, Kb, Vtb, Yb);
  proj_gemm_kernel<<<dim3(32, 16), 256, 0, stream>>>(Yb, WtP, b_proj, out);
}

// Round 9
// 167.524 us; speedup vs baseline: 1.0665x; 1.0665x over previous
//
#include <hip/hip_runtime.h>
#include <hip/hip_bf16.h>

// TurnGPT attention block: y = proj(softmax(causal(QK^T/8)) V), qkv = x@W_attn+b
// B=2, T=2048, C=1024, H=16, D=64. d_in/d_out are FP32; bf16 MFMA inside.
// Q pre-scaled by 0.125*log2(e) at the qkv epilogue: attn p = exp2(s) raw.
// qkv: 256x192 tile, BK=64 (grid 16x16 = 1 block/CU), 8 waves, acc[4][6] (r7).
// attn: swapped QK^T (mfma(K,Q)) -> P lane-local (q=l15); PV consumes pa
//   directly. The k-permutation sigma(j)=(j>>3)*4+(j&3)+16*((j>>2)&1) is
//   baked into Vt's GLOBAL layout (qkv epilogue permutes t within 32-blocks,
//   ushort4 groups preserved), so attn's V read is a single b128 at the same
//   rsw-swizzled address as the K read. r8's split-b64 V reads were a 4-way
//   bank conflict (532K -> 4.26M cycles) that cancelled the P-roundtrip win.
// proj single-buf (r1), attn qt-paired (r1). Hand vmcnt pipelines REGRESSED
// (r3) -> plain __syncthreads only.

typedef __bf16 bf16_t;
typedef __bf16 bf16x8 __attribute__((ext_vector_type(8)));
typedef float f32x4 __attribute__((ext_vector_type(4)));
typedef unsigned short ushort_t;

#define QSCALE 0.18033688011f   // 0.125 * log2(e)

__device__ __forceinline__ void glds16(const bf16_t* g, ushort_t* l) {
  __builtin_amdgcn_global_load_lds(
      (const __attribute__((address_space(1))) unsigned int*)g,
      (__attribute__((address_space(3))) unsigned int*)l, 16, 0, 0);
}

// ---------------- fused prep: cvt(x) + transpose_cvt(W_attn) + (W_proj) ------
__global__ __launch_bounds__(256) void prep_kernel(
    const float* __restrict__ x, const float* __restrict__ W_attn,
    const float* __restrict__ W_proj, ushort_t* __restrict__ Xb,
    ushort_t* __restrict__ WtA, ushort_t* __restrict__ WtP) {
  const int bid = blockIdx.x, tid = threadIdx.x;
  if (bid < 4096) {
    int i = bid * 256 + tid;
    float4 v = ((const float4*)x)[i];
    ushort4 o;
    o.x = __builtin_bit_cast(unsigned short, (bf16_t)v.x);
    o.y = __builtin_bit_cast(unsigned short, (bf16_t)v.y);
    o.z = __builtin_bit_cast(unsigned short, (bf16_t)v.z);
    o.w = __builtin_bit_cast(unsigned short, (bf16_t)v.w);
    ((ushort4*)Xb)[i] = o;
    return;
  }
  __shared__ ushort_t tile[32][33];
  const float* in;
  ushort_t* out;
  int C, bx, by;
  if (bid < 4096 + 3072) { int idx = bid - 4096; in = W_attn; out = WtA; C = 3072; bx = idx % 96; by = idx / 96; }
  else                   { int idx = bid - 7168; in = W_proj; out = WtP; C = 1024; bx = idx % 32; by = idx / 32; }
  const int tx = tid & 31, ty = tid >> 5;
  int cbase = bx * 32, rbase = by * 32;
#pragma unroll
  for (int i = ty; i < 32; i += 8)
    tile[i][tx] = __builtin_bit_cast(
        unsigned short, (bf16_t)in[(size_t)(rbase + i) * C + cbase + tx]);
  __syncthreads();
#pragma unroll
  for (int i = ty; i < 32; i += 8)
    out[(size_t)(cbase + i) * 1024 + rbase + tx] = tile[tx][i];
}

// ------- QKV GEMM: Xb[4096,1024] @ W_attn + b, 256x192 tiles, BK=64 ----------
__global__ __launch_bounds__(512) void qkv_gemm_kernel(
    const bf16_t* __restrict__ X, const bf16_t* __restrict__ WtA,
    const float* __restrict__ bias, bf16_t* __restrict__ Qd,
    bf16_t* __restrict__ Kd, bf16_t* __restrict__ Vtd) {
  __shared__ ushort_t As[2 * 2 * 256 * 32];   // 64 KB: buf stride 16384
  __shared__ ushort_t Bs[2 * 2 * 192 * 32];   // 48 KB: buf stride 12288
  const int tid  = threadIdx.x;
  const int lane = tid & 63, wave = tid >> 6;
  const int l15  = lane & 15, quad = lane >> 4;
  const int wrow = (wave >> 1) * 64;      // 4 M-waves: 0,64,128,192
  const int wcol = (wave & 1) * 96;       // 2 N-waves: 0,96
  const int mtile = blockIdx.x * 256, ntile = blockIdx.y * 192;
  const int K = 1024;
  const int lr4 = lane >> 2;                               // row in stripe
  const int csw = ((lane & 3) ^ ((lr4 >> 1) & 3)) * 8;     // swizzled src col
  const int rsw = (quad ^ ((l15 >> 1) & 3)) * 8;           // swizzled read
  const bf16_t* Xrow = X   + (size_t)(mtile + lr4) * K + csw;
  const bf16_t* Wrow = WtA + (size_t)(ntile + lr4) * K + csw;

#define STAGE_QKV(kb, Asl, Bsl)                                              \
  {                                                                          \
    _Pragma("unroll")                                                        \
    for (int kk = 0; kk < 7; kk++) {                                         \
      int s = wave + kk * 8;                                                 \
      if (s < 32) {                                                          \
        int hh = s >> 4, r16 = s & 15;                                       \
        glds16(Xrow + (size_t)(r16 * 16) * K + (kb) + hh * 32,               \
               (Asl) + hh * 8192 + r16 * 512);                               \
      } else {                                                               \
        int sb = s - 32;                                                     \
        int hh = (sb >= 12) ? 1 : 0, r12 = sb - hh * 12;                     \
        glds16(Wrow + (size_t)(r12 * 16) * K + (kb) + hh * 32,               \
               (Bsl) + hh * 6144 + r12 * 512);                               \
      }                                                                      \
    }                                                                        \
  }

  f32x4 acc[4][6] = {};
  STAGE_QKV(0, As, Bs);                    // prologue: kt=0 -> buf 0
  __syncthreads();
  for (int kt = 0; kt < 16; kt++) {
    const int cur = kt & 1, nxt = cur ^ 1;
    if (kt + 1 < 16)                       // issue prefetch FIRST
      STAGE_QKV((kt + 1) * 64, As + nxt * 16384, Bs + nxt * 12288);
#pragma unroll
    for (int hh = 0; hh < 2; hh++) {
      bf16x8 af[4], bfr[6];
#pragma unroll
      for (int i = 0; i < 4; i++)
        af[i] = *(const bf16x8*)&As[cur * 16384 + hh * 8192 + (wrow + i * 16 + l15) * 32 + rsw];
#pragma unroll
      for (int j = 0; j < 6; j++)
        bfr[j] = *(const bf16x8*)&Bs[cur * 12288 + hh * 6144 + (wcol + j * 16 + l15) * 32 + rsw];
#pragma unroll
      for (int i = 0; i < 4; i++)
#pragma unroll
        for (int j = 0; j < 6; j++)
          acc[i][j] = __builtin_amdgcn_mfma_f32_16x16x32_bf16(af[i], bfr[j], acc[i][j], 0, 0, 0);
    }
    __syncthreads();          // drains prefetch vmcnt AFTER compute + barrier
  }
#undef STAGE_QKV

  const int b = mtile >> 11;               // block-uniform (256 | 2048)
#pragma unroll
  for (int j = 0; j < 6; j++) {
    int n = ntile + wcol + j * 16 + l15;   // [0,3072)
    float bv = bias[n];
    int sec = n >> 10, cc = n & 1023, h = cc >> 6, d = cc & 63;
    size_t bh = (size_t)(b * 16 + h);
    if (sec == 2) {
      // V: sigma-permuted t within each 32-block (k-perm for attn PV b128
      // reads). t = base64 + 32*(i>>1) + {16*(i&1) + 4*quad + s} maps to
      // j = base64 + 32*(i>>1) + {8*quad + 4*(i&1) + s}; s=0..3 contiguous
      // -> ushort4 store preserved.
#pragma unroll
      for (int i = 0; i < 4; i++) {
        int tperm = (mtile & 2047) + wrow + ((i >> 1) << 5) + (quad << 3) + ((i & 1) << 2);
        ushort4 o4;
        o4.x = __builtin_bit_cast(unsigned short, (bf16_t)(acc[i][j][0] + bv));
        o4.y = __builtin_bit_cast(unsigned short, (bf16_t)(acc[i][j][1] + bv));
        o4.z = __builtin_bit_cast(unsigned short, (bf16_t)(acc[i][j][2] + bv));
        o4.w = __builtin_bit_cast(unsigned short, (bf16_t)(acc[i][j][3] + bv));
        *(ushort4*)&Vtd[(bh * 64 + d) * 2048 + tperm] = o4;
      }
    } else {
      const float sv = (sec == 0) ? QSCALE : 1.0f;
      bf16_t* Od = (sec == 0) ? Qd : Kd;
#pragma unroll
      for (int i = 0; i < 4; i++) {
#pragma unroll
        for (int r = 0; r < 4; r++) {
          int t = (mtile & 2047) + wrow + i * 16 + quad * 4 + r;
          Od[(bh * 2048 + t) * 64 + d] = (bf16_t)((acc[i][j][r] + bv) * sv);
        }
      }
    }
  }
}

// ---------------- flash attention: swapped QK^T, P in-register --------------
// Swapped QK (mfma(K,Q)): score tile C[k][q]: lane col l15 = q, rows
// quad*4+r = k (within 16). Each lane holds 8 P-values of ONE q-row.
// PV A slot e needs k = sigma(quad*8+e) = quad*4+(e&3)+16*(e>>2): pa[r]=p0,
// pa[4+r]=p1 matches. V's global layout is sigma-permuted (qkv epilogue),
// so the B-operand is one b128 at the K-read's rsw swizzle (conflict-free
// profile; r8's split-b64 pattern was 4-way conflicted).
// Softmax denom: one scalar per lane (q=l15), shfl_xor(16,32) reduce.
// qt pairing (r1): y<16 -> qt=15-x, y>=16 -> qt=x: uniform 34 units/CU.
__global__ __launch_bounds__(512) void attn_kernel(
    const bf16_t* __restrict__ Q, const bf16_t* __restrict__ K,
    const bf16_t* __restrict__ Vt, bf16_t* __restrict__ Y) {
  __shared__ ushort_t Ks[2][4096];       // [buf][kc*2048 + t*32 + chunk]
  __shared__ ushort_t Vs[2][4096];       // [buf][tHalf*2048 + d*32 + chunk]
  const int bh = blockIdx.y;
  const int qt = (blockIdx.y < 16) ? (15 - (int)blockIdx.x) : (int)blockIdx.x;
  const int tid = threadIdx.x, wave = tid >> 6, lane = tid & 63;
  const int l15 = lane & 15, quad = lane >> 4;
  const bf16_t* Qh = Q + (size_t)bh * 2048 * 64;
  const bf16_t* Kh = K + (size_t)bh * 2048 * 64;
  const bf16_t* Vh = Vt + (size_t)bh * 64 * 2048;
  const int b = bh >> 4, h = bh & 15;
  const int qw = qt * 128 + wave * 16;   // wave's q-row base
  const int nkt = 2 * qt + 2;            // 64-wide k-tiles

  bf16x8 qa[2];
#pragma unroll
  for (int kc = 0; kc < 2; kc++)
    qa[kc] = *(const bf16x8*)(Qh + (size_t)(qw + l15) * 64 + kc * 32 + quad * 8);

  f32x4 o[4] = {};
  float lp = 0.f;                        // denom for q = qw + l15
  const int rsw = (quad ^ ((l15 >> 1) & 3)) * 8;   // swizzled read chunk

  // staging: waves 0-3 -> K, waves 4-7 -> V; 2 glds16/wave/tile, swizzled cols
  const int lr4 = lane >> 2;
  const int csw = ((lane & 3) ^ ((lr4 >> 1) & 3)) * 8;
  const bool isK = wave < 4;
  const int sw = isK ? wave : wave - 4;
  const int rbase = (sw & 1) * 32;
  const bf16_t* gp0;
  size_t rowstep;
  if (isK) { gp0 = Kh + (size_t)(rbase + lr4) * 64 + (sw >> 1) * 32 + csw;  rowstep = 64; }
  else     { gp0 = Vh + (size_t)(rbase + lr4) * 2048 + (sw >> 1) * 32 + csw; rowstep = 2048; }
  const size_t kstep = isK ? (size_t)64 * 64 : 64;
  ushort_t* dst0 = (isK ? Ks[0] : Vs[0]) + (sw >> 1) * 2048 + rbase * 32;
  ushort_t* dst1 = (isK ? Ks[1] : Vs[1]) + (sw >> 1) * 2048 + rbase * 32;

#pragma unroll
  for (int c = 0; c < 2; c++)                       // prologue: tile 0 -> buf 0
    glds16(gp0 + (size_t)(c * 16) * rowstep, dst0 + c * 512);

  f32x4 zz = {0.f, 0.f, 0.f, 0.f};
  for (int kt = 0; kt < nkt; kt++) {
    const int cur = kt & 1;
    __syncthreads();                                // cur buf visible
    if (kt + 1 < nkt) {
      ushort_t* nd = cur ? dst0 : dst1;
#pragma unroll
      for (int c = 0; c < 2; c++)
        glds16(gp0 + (size_t)(kt + 1) * kstep + (size_t)(c * 16) * rowstep, nd + c * 512);
    }
#pragma unroll
    for (int h32 = 0; h32 < 2; h32++) {
      const int kb32 = kt * 64 + h32 * 32;          // sub-tile k base
      if (kb32 > qw + 15) break;                    // wave-uniform skip
      bf16x8 kb[2][2];
#pragma unroll
      for (int bn = 0; bn < 2; bn++)
#pragma unroll
        for (int kc = 0; kc < 2; kc++)
          kb[bn][kc] = *(const bf16x8*)&Ks[cur][kc * 2048 + (h32 * 32 + bn * 16 + l15) * 32 + rsw];
      f32x4 s[2];
#pragma unroll
      for (int bn = 0; bn < 2; bn++) {              // SWAPPED: K as A, Q as B
        f32x4 t0 = __builtin_amdgcn_mfma_f32_16x16x32_bf16(kb[bn][0], qa[0], zz, 0, 0, 0);
        s[bn] = __builtin_amdgcn_mfma_f32_16x16x32_bf16(kb[bn][1], qa[1], t0, 0, 0, 0);
      }
      const bool dg = (kb32 + 31 > qw);
      const int qrow = qw + l15;                    // this lane's q-row
      bf16x8 pa;
#pragma unroll
      for (int r = 0; r < 4; r++) {
        float v0 = s[0][r];                         // k = kb32 + quad*4 + r
        float v1 = s[1][r];                         // k = kb32 + 16 + quad*4 + r
        if (dg) {
          int k0 = kb32 + quad * 4 + r;
          if (k0 > qrow) v0 = -1e5f;
          if (k0 + 16 > qrow) v1 = -1e5f;
        }
        float p0 = __builtin_amdgcn_exp2f(v0);      // Q pre-scaled: exp2-domain
        float p1 = __builtin_amdgcn_exp2f(v1);
        lp += p0 + p1;
        pa[r]     = (bf16_t)p0;                     // A slot e=r   -> k=quad*4+r
        pa[4 + r] = (bf16_t)p1;                     // A slot e=4+r -> k=16+quad*4+r
      }
#pragma unroll
      for (int ns = 0; ns < 4; ns++) {              // V sigma-permuted: one b128
        bf16x8 vb = *(const bf16x8*)&Vs[cur][h32 * 2048 + (ns * 16 + l15) * 32 + rsw];
        o[ns] = __builtin_amdgcn_mfma_f32_16x16x32_bf16(pa, vb, o[ns], 0, 0, 0);
      }
    }
  }
  // epilogue: reduce lp across quads (q=l15), redistribute to C layout rows
  lp += __shfl_xor(lp, 16);
  lp += __shfl_xor(lp, 32);
  float inv_l = 1.0f / fmaxf(lp, 1e-30f);
#pragma unroll
  for (int r = 0; r < 4; r++) {
    float il = __shfl(inv_l, quad * 4 + r);         // l for q-row quad*4+r
    int t = qw + quad * 4 + r;
#pragma unroll
    for (int ns = 0; ns < 4; ns++) {
      int c = h * 64 + ns * 16 + l15;
      Y[((size_t)(b * 2048 + t)) * 1024 + c] = (bf16_t)(o[ns][r] * il);
    }
  }
}

// ---------------- proj GEMM: 128x64 tiles, single-buf 2-barrier (round-1) ----
__global__ __launch_bounds__(256) void proj_gemm_kernel(
    const bf16_t* __restrict__ Yb, const bf16_t* __restrict__ WtP,
    const float* __restrict__ bias, float* __restrict__ out) {
  __shared__ ushort_t As[128 * 32];
  __shared__ ushort_t Bs[64 * 32];
  const int tid = threadIdx.x;
  const int lane = tid & 63, wave = tid >> 6;
  const int l15 = lane & 15, quad = lane >> 4;
  const int wrow = (wave >> 1) * 64, wcol = (wave & 1) * 32;
  const int mtile = blockIdx.x * 128, ntile = blockIdx.y * 64;
  const int K = 1024;
  const int lr = lane >> 2;
  const int lc = (((lane & 3) ^ ((lr >> 1) & 3)) * 8);
  const bf16_t* Ap = Yb + (size_t)(mtile + wave * 32 + lr) * K + lc;
  const bf16_t* Bp = WtP + (size_t)(ntile + wave * 16 + lr) * K + lc;
  const int rsw = (quad ^ ((l15 >> 1) & 3)) * 8;
  ushort_t* Asw = As + wave * 32 * 32;
  ushort_t* Bsw = Bs + wave * 16 * 32;
  f32x4 acc[4][2] = {};
  for (int kb = 0; kb < K; kb += 32) {
    __syncthreads();
    glds16(Ap + kb, Asw);
    glds16(Ap + (size_t)16 * K + kb, Asw + 16 * 32);
    glds16(Bp + kb, Bsw);
    __syncthreads();
    bf16x8 af[4], bfr[2];
#pragma unroll
    for (int i = 0; i < 4; i++)
      af[i] = *(const bf16x8*)&As[(wrow + i * 16 + l15) * 32 + rsw];
#pragma unroll
    for (int j = 0; j < 2; j++)
      bfr[j] = *(const bf16x8*)&Bs[(wcol + j * 16 + l15) * 32 + rsw];
#pragma unroll
    for (int i = 0; i < 4; i++)
#pragma unroll
      for (int j = 0; j < 2; j++)
        acc[i][j] = __builtin_amdgcn_mfma_f32_16x16x32_bf16(af[i], bfr[j], acc[i][j], 0, 0, 0);
  }
#pragma unroll
  for (int j = 0; j < 2; j++) {
    int n = ntile + wcol + j * 16 + l15;
    float bv = bias[n];
#pragma unroll
    for (int i = 0; i < 4; i++) {
#pragma unroll
      for (int r = 0; r < 4; r++) {
        int m = mtile + wrow + i * 16 + quad * 4 + r;
        out[(size_t)m * 1024 + n] = acc[i][j][r] + bv;
      }
    }
  }
}

extern "C" void kernel_launch(void* const* d_in, const int* in_sizes, int n_in,
                              void* d_out, int out_size, void* d_ws, size_t ws_size,
                              hipStream_t stream) {
  const float* x      = (const float*)d_in[0];   // [2,2048,1024]
  const float* W_attn = (const float*)d_in[1];   // [1024,3072]
  const float* b_attn = (const float*)d_in[2];   // [3072]
  const float* W_proj = (const float*)d_in[3];   // [1024,1024]
  const float* b_proj = (const float*)d_in[4];   // [1024]
  float* out = (float*)d_out;                    // [2,2048,1024]

  bf16_t* ws  = (bf16_t*)d_ws;
  bf16_t* WtA = ws;                                // 3072*1024
  bf16_t* WtP = WtA + (size_t)3072 * 1024;         // 1024*1024
  bf16_t* Xb  = WtP + (size_t)1024 * 1024;         // 4096*1024
  bf16_t* Qb  = Xb + (size_t)4194304;
  bf16_t* Kb  = Qb + (size_t)4194304;
  bf16_t* Vtb = Kb + (size_t)4194304;
  bf16_t* Yb  = Vtb + (size_t)4194304;             // ~48 MB bf16 total

  prep_kernel<<<8192, 256, 0, stream>>>(x, W_attn, W_proj,
      (ushort_t*)Xb, (ushort_t*)WtA, (ushort_t*)WtP);
  qkv_gemm_kernel<<<dim3(16, 16), 512, 0, stream>>>(Xb, WtA, b_attn, Qb, Kb, Vtb);
  attn_kernel<<<dim3(16, 32), 512, 0, stream>>>(Qb, Kb, Vtb, Yb);
  proj_gemm_kernel<<<dim3(32, 16), 256, 0, stream>>>(Yb, WtP, b_proj, out);
}